// Round 15
// baseline (152.599 us; speedup 1.0000x reference)
//
#include <hip/hip_runtime.h>

// Shapes
#define NB   256      // batch
#define E0   300      // embedding
#define EP   304      // padded embedding
#define F_   512      // features
#define KP   1536     // padded K (5*304=1520 -> 48 ksubs of 32 / 12 ss of 128)
#define NKT  48
#define LQ_  64
#define LA_  256

typedef __attribute__((ext_vector_type(4))) float f32x4;
typedef __attribute__((ext_vector_type(8))) short short8;

#define XQ_ELEMS (NB * (LQ_ + 4) * EP)   // 5,292,032
#define XA_ELEMS (NB * (LA_ + 4) * EP)   // 20,234,240
#define WF_ELEMS (F_ * KP)               // 786,432 (16f-fragment-packed)
#define OUTQ_ELEMS ((size_t)NB * F_ * LQ_)
#define XROWS (NB * (LQ_ + 4) + NB * (LA_ + 4))   // 83,968
#define XPBLK 24928                      // XROWS*76/256 (exact)
#define WPBLK 3072                       // WF_ELEMS/256

__device__ __forceinline__ unsigned short f2bf(float x) {
    unsigned int u = __float_as_uint(x);
    u = u + 0x7fffu + ((u >> 16) & 1u);   // RNE
    return (unsigned short)(u >> 16);
}

// Fused prep: x-part (verified r6-r14) + W-fragment part (verified r5-r14).
__global__ void prep_all(const float* __restrict__ q, const float* __restrict__ a,
                         const float* __restrict__ W,
                         unsigned short* __restrict__ xq, unsigned short* __restrict__ xa,
                         unsigned short* __restrict__ wfr)
{
    const int bid = blockIdx.x;
    if (bid < XPBLK) {
        int idx = bid * 256 + threadIdx.x;
        int row = idx / 76;
        int col = idx - row * 76;
        const float* src;
        unsigned short* dst;
        bool valid;
        if (row < NB * (LQ_ + 4)) {
            int b = row / (LQ_ + 4), lp = row - b * (LQ_ + 4);
            dst = xq + (size_t)row * EP;
            valid = (lp >= 2 && lp < 2 + LQ_);
            src = q + ((size_t)b * LQ_ + (lp - 2)) * E0;
        } else {
            int r2 = row - NB * (LQ_ + 4);
            int b = r2 / (LA_ + 4), lp = r2 - b * (LA_ + 4);
            dst = xa + (size_t)r2 * EP;
            valid = (lp >= 2 && lp < 2 + LA_);
            src = a + ((size_t)b * LA_ + (lp - 2)) * E0;
        }
        unsigned long long pk = 0ull;
        if (valid && col < 75) {
            const float4 v = reinterpret_cast<const float4*>(src)[col];
            pk = (unsigned long long)f2bf(v.x)
               | ((unsigned long long)f2bf(v.y) << 16)
               | ((unsigned long long)f2bf(v.z) << 32)
               | ((unsigned long long)f2bf(v.w) << 48);
        }
        *reinterpret_cast<unsigned long long*>(dst + (size_t)col * 4) = pk;
    } else {
        int idx = (bid - XPBLK) * 256 + threadIdx.x;
        int j    = idx & 7;
        int lane = (idx >> 3) & 63;
        int chunk = idx >> 9;
        int kc = chunk % NKT;
        int tile16 = chunk / NKT;
        int f  = tile16 * 16 + (lane & 15);
        int kp = kc * 32 + (lane >> 4) * 8 + j;
        int jj = kp / EP;
        int e  = kp - jj * EP;
        float v = (kp < 5 * EP && e < E0) ? W[(size_t)(jj * E0 + e) * F_ + f] : 0.f;
        wfr[idx] = f2bf(v);
    }
}

// r15: 256f x 80l tile, 4 waves (wave = 64f x 80l, acc[4][5], 20 mfma/fence),
// ring-2 LDS 40 KB, 2 blocks/CU, grid 2048 = EXACTLY 4 rounds of 512 slots
// (kills the r14 2.5-round tail).  Q/A straddling tiles handled per-row.
// W path identical to r14 (2 sets, reloaded 2-ksubs-ahead after use).
// Z: 20 stage units/SS (kb 0..3 x rg 0..4 of [80][32] blocks), 5 per wave.
// Per-wave in-order VM ledger (ST5 = 5 loads, W4 = 4 loads):
//   Steady entry to SS S: [W4@ks2(S-1), W4@ks3(S-1)] = 8.  +ST5(S+1) = 13.
//   F0 vmcnt(9): retires W4@ks2(S-1) (wA ks0).       +W4A -> 13.
//   F1 vmcnt(9): retires W4@ks3(S-1) (wB ks1).       +W4B -> 13.
//   F2 vmcnt(4): retires ST5(S+1) (publication before end-of-S barrier)
//                AND W4@ks0 (wA ks2).                +W4A -> 8.
//   F3 vmcnt(4): retires W4@ks1 (wB ks3).            +W4B -> 8 = entry.
//   lgkm 5,5,5,0 (blk reads 5-deep; ks3 drains blk3 -> WAR-safe for next ST5
//   into buf (S+1)&1, read in S-1, drained before that SS's end barrier).
//   Prologue: W4A(k0), W4B(k1), ST5(0) -> vmcnt(0), barrier.
//   SS11: no ST5; fences 4,4,4,0; W4 only at ks0 (k46), ks1 (k47).
__global__ __launch_bounds__(256, 2) void qa_gemm(
    const unsigned short* __restrict__ xq,
    const unsigned short* __restrict__ xa,
    const unsigned short* __restrict__ wfr,
    const float* __restrict__ bias,
    float* __restrict__ out)
{
    __shared__ __align__(16) unsigned short lds[2 * 10240];   // 40 KB Z-ring

    const int bid = blockIdx.x;
    const int wg  = (bid & 7) * 256 + (bid >> 3);   // XCD swizzle, 2048 % 8 == 0

    const int ftBase = (wg & 1) * 256;
    const int Mb     = (wg >> 1) * 80;              // 0..81840

    const int tid  = threadIdx.x;
    const int lane = tid & 63;
    const int wid  = tid >> 6;      // wave = 64f slice; all share the 80l tile
    const int lq   = lane >> 4;
    const int lr   = lane & 15;
    const int s_c  = (lane & 3) ^ ((lane >> 3) & 3);
    const int sub  = lane >> 2;

    // ---- Z staging: 5 units (of 20) per wave; unit u = kb*5+rg
    const unsigned short* gzu[5];
    int dzu[5];
#pragma unroll
    for (int i = 0; i < 5; ++i) {
        const int u  = wid + 4 * i;
        const int kb = u / 5;
        const int rg = u - kb * 5;
        const int m  = Mb + rg * 16 + sub;
        const unsigned short* p;
        if (m < 16384) { int b = m >> 6, l = m & 63;            p = xq + (size_t)(b * (LQ_ + 4) + l) * EP; }
        else { int m2 = m - 16384; int b = m2 >> 8, l = m2 & 255; p = xa + (size_t)(b * (LA_ + 4) + l) * EP; }
        gzu[i] = p + kb * 32 + s_c * 8;
        dzu[i] = kb * 2560 + rg * 512;   // shorts within a buf
    }

#define GLLDS(p, d) __builtin_amdgcn_global_load_lds(                               \
        (const __attribute__((address_space(1))) void*)(p),                         \
        (__attribute__((address_space(3))) void*)(d), 16, 0, 0)
#define ST5(T) do { const int rb = ((T) & 1) * 10240; const size_t ko = (size_t)(T) * 128; \
    _Pragma("unroll") for (int i = 0; i < 5; ++i)                                   \
        GLLDS(gzu[i] + ko, lds + rb + dzu[i]); } while (0)

    // ---- W fragment chains (verified layout); 2 sets, stride 2 kc per load
    const unsigned short* wpA0 = wfr + (size_t)((ftBase >> 4) + wid * 4 + 0) * NKT * 512 + lane * 8;
    const unsigned short* wpA1 = wfr + (size_t)((ftBase >> 4) + wid * 4 + 1) * NKT * 512 + lane * 8;
    const unsigned short* wpA2 = wfr + (size_t)((ftBase >> 4) + wid * 4 + 2) * NKT * 512 + lane * 8;
    const unsigned short* wpA3 = wfr + (size_t)((ftBase >> 4) + wid * 4 + 3) * NKT * 512 + lane * 8;
    const unsigned short* wpB0 = wpA0 + 512;
    const unsigned short* wpB1 = wpA1 + 512;
    const unsigned short* wpB2 = wpA2 + 512;
    const unsigned short* wpB3 = wpA3 + 512;

#define WLOAD(dst, p) do {                                                           \
    asm volatile("global_load_dwordx4 %0, %1, off" : "=v"(dst) : "v"(p) : "memory"); \
    (p) += 1024; } while (0)
#define W4A do { WLOAD(wA[0], wpA0); WLOAD(wA[1], wpA1);                             \
                 WLOAD(wA[2], wpA2); WLOAD(wA[3], wpA3); } while (0)
#define W4B do { WLOAD(wB[0], wpB0); WLOAD(wB[1], wpB1);                             \
                 WLOAD(wB[2], wpB2); WLOAD(wB[3], wpB3); } while (0)

    // ---- Z fragment LDS offsets (r8-verified family; 5 nt frags)
    const int cs = (lq ^ ((lr >> 1) & 3)) * 16;
    int zoff[5];
#pragma unroll
    for (int n = 0; n < 5; ++n) zoff[n] = (n * 16 + lr) * 64 + cs;

#define ZRD5(DST, BLK) do { _Pragma("unroll") for (int n = 0; n < 5; ++n)            \
    DST[n] = *(const short8*)(bbase + (BLK) * 5120 + zoff[n]); } while (0)
#define SB __builtin_amdgcn_sched_barrier(0)
#define FENCE(VM, LG) do {                                                           \
    asm volatile("s_waitcnt vmcnt(" #VM ") lgkmcnt(" #LG ")" ::: "memory"); SB; } while (0)
#define MFMA20(WU, ZU) do { __builtin_amdgcn_s_setprio(1);                           \
    _Pragma("unroll") for (int mf = 0; mf < 4; ++mf)                                 \
    _Pragma("unroll") for (int nt = 0; nt < 5; ++nt)                                 \
        acc[mf][nt] = __builtin_amdgcn_mfma_f32_16x16x32_bf16(                       \
            WU[mf], ZU[nt], acc[mf][nt], 0, 0, 0);                                   \
    __builtin_amdgcn_s_setprio(0); SB; } while (0)

    f32x4 acc[4][5] = {};
    short8 zA[5], zB[5], wA[4], wB[4];

    // Prologue: wA(k0), wB(k1), stage ss0; drain; publish.
    W4A; W4B;
    ST5(0);
    asm volatile("s_waitcnt vmcnt(0)\n\ts_barrier" ::: "memory");

    for (int S = 0; S < 11; ++S) {
        ST5(S + 1);
        const char* bbase = (const char*)lds + (S & 1) * 20480;
        ZRD5(zA, 0);
        /* ks0 */ ZRD5(zB, 1); FENCE(9, 5); MFMA20(wA, zA); W4A;
        /* ks1 */ ZRD5(zA, 2); FENCE(9, 5); MFMA20(wB, zB); W4B;
        /* ks2 */ ZRD5(zB, 3); FENCE(4, 5); MFMA20(wA, zA); W4A;
        /* ks3 */              FENCE(4, 0); MFMA20(wB, zB); W4B;
        asm volatile("s_barrier" ::: "memory");
    }
    {   // SS 11: no stage; W4 only at ks0 (k46) and ks1 (k47)
        const char* bbase = (const char*)lds + 20480;
        ZRD5(zA, 0);
        /* ks0 */ ZRD5(zB, 1); FENCE(4, 5); MFMA20(wA, zA); W4A;
        /* ks1 */ ZRD5(zA, 2); FENCE(4, 5); MFMA20(wB, zB); W4B;
        /* ks2 */ ZRD5(zB, 3); FENCE(4, 5); MFMA20(wA, zA);
        /* ks3 */              FENCE(0, 0); MFMA20(wB, zB);
    }

#undef MFMA20
#undef FENCE
#undef SB
#undef ZRD5
#undef W4A
#undef W4B
#undef WLOAD
#undef ST5
#undef GLLDS

    // ---- epilogue: D row = f = lq*4+reg, col = l = lr (verified r1-r14);
    //      per-nt region select (tiles may straddle the Q/A boundary)
#pragma unroll
    for (int nt = 0; nt < 5; ++nt) {
        const int m = Mb + nt * 16 + lr;
        float* orow;
        int sh;
        if (m < 16384) { int b = m >> 6, l = m & 63;
            orow = out + (((size_t)b * F_) << 6) + l; sh = 6; }
        else { int m2 = m - 16384; int b = m2 >> 8, l = m2 & 255;
            orow = out + OUTQ_ELEMS + (((size_t)b * F_) << 8) + l; sh = 8; }
#pragma unroll
        for (int mf = 0; mf < 4; ++mf) {
            const int f0 = ftBase + wid * 64 + mf * 16 + lq * 4;
            const f32x4 v = acc[mf][nt];
#pragma unroll
            for (int r = 0; r < 4; ++r)
                orow[(size_t)(f0 + r) << sh] = v[r] + __ldg(&bias[f0 + r]);
        }
    }
}

extern "C" void kernel_launch(void* const* d_in, const int* in_sizes, int n_in,
                              void* d_out, int out_size, void* d_ws, size_t ws_size,
                              hipStream_t stream)
{
    const float* q    = (const float*)d_in[0];
    const float* a    = (const float*)d_in[1];
    const float* W    = (const float*)d_in[2];
    const float* bias = (const float*)d_in[3];
    float* out = (float*)d_out;

    unsigned short* xq  = (unsigned short*)d_ws;
    unsigned short* xa  = xq + XQ_ELEMS;
    unsigned short* wfr = xa + XA_ELEMS;
    // ws needed: (XQ+XA+WF)*2 = 52.6 MB.  xa K-pad tail reads overrun <=32 B
    // into wfr: in-bounds; the matching W fragments are zero -> don't-care.

    prep_all<<<XPBLK + WPBLK, 256, 0, stream>>>(q, a, W, xq, xa, wfr);
    qa_gemm<<<2048, 256, 0, stream>>>(xq, xa, wfr, bias, out);
}

// Round 16
// 151.792 us; speedup vs baseline: 1.0053x; 1.0053x over previous
//
#include <hip/hip_runtime.h>

// Shapes
#define NB   256      // batch
#define E0   300      // embedding
#define EP   304      // padded embedding
#define F_   512      // features
#define KP   1536     // padded K (5*304=1520 -> 48 ksubs of 32 / 12 ss of 128)
#define NKT  48
#define LQ_  64
#define LA_  256

typedef __attribute__((ext_vector_type(4))) float f32x4;
typedef __attribute__((ext_vector_type(8))) short short8;

#define XQ_ELEMS (NB * (LQ_ + 4) * EP)   // 5,292,032
#define XA_ELEMS (NB * (LA_ + 4) * EP)   // 20,234,240
#define WF_ELEMS (F_ * KP)               // 786,432 (16f-fragment-packed)
#define OUTQ_ELEMS ((size_t)NB * F_ * LQ_)
#define XROWS (NB * (LQ_ + 4) + NB * (LA_ + 4))   // 83,968
#define XPBLK 24928                      // XROWS*76/256 (exact)
#define WPBLK 3072                       // WF_ELEMS/256

__device__ __forceinline__ unsigned short f2bf(float x) {
    unsigned int u = __float_as_uint(x);
    u = u + 0x7fffu + ((u >> 16) & 1u);   // RNE
    return (unsigned short)(u >> 16);
}

// Fused prep: x-part (verified r6-r15) + W-fragment part (verified r5-r15).
__global__ void prep_all(const float* __restrict__ q, const float* __restrict__ a,
                         const float* __restrict__ W,
                         unsigned short* __restrict__ xq, unsigned short* __restrict__ xa,
                         unsigned short* __restrict__ wfr)
{
    const int bid = blockIdx.x;
    if (bid < XPBLK) {
        int idx = bid * 256 + threadIdx.x;
        int row = idx / 76;
        int col = idx - row * 76;
        const float* src;
        unsigned short* dst;
        bool valid;
        if (row < NB * (LQ_ + 4)) {
            int b = row / (LQ_ + 4), lp = row - b * (LQ_ + 4);
            dst = xq + (size_t)row * EP;
            valid = (lp >= 2 && lp < 2 + LQ_);
            src = q + ((size_t)b * LQ_ + (lp - 2)) * E0;
        } else {
            int r2 = row - NB * (LQ_ + 4);
            int b = r2 / (LA_ + 4), lp = r2 - b * (LA_ + 4);
            dst = xa + (size_t)r2 * EP;
            valid = (lp >= 2 && lp < 2 + LA_);
            src = a + ((size_t)b * LA_ + (lp - 2)) * E0;
        }
        unsigned long long pk = 0ull;
        if (valid && col < 75) {
            const float4 v = reinterpret_cast<const float4*>(src)[col];
            pk = (unsigned long long)f2bf(v.x)
               | ((unsigned long long)f2bf(v.y) << 16)
               | ((unsigned long long)f2bf(v.z) << 32)
               | ((unsigned long long)f2bf(v.w) << 48);
        }
        *reinterpret_cast<unsigned long long*>(dst + (size_t)col * 4) = pk;
    } else {
        int idx = (bid - XPBLK) * 256 + threadIdx.x;
        int j    = idx & 7;
        int lane = (idx >> 3) & 63;
        int chunk = idx >> 9;
        int kc = chunk % NKT;
        int tile16 = chunk / NKT;
        int f  = tile16 * 16 + (lane & 15);
        int kp = kc * 32 + (lane >> 4) * 8 + j;
        int jj = kp / EP;
        int e  = kp - jj * EP;
        float v = (kp < 5 * EP && e < E0) ? W[(size_t)(jj * E0 + e) * F_ + f] : 0.f;
        wfr[idx] = f2bf(v);
    }
}

// r16: r14 base (256f x 128l, 4 waves, acc[4][8], ring-2 64 KB, 2 blocks/CU,
// grid 1280) with MERGED FENCES: 2 fences/SS, 64 MFMA per fence region.
// Per-wave in-order VM ledger (ST8 = 8 loads, W4 = 4 loads):
//   SS entry outstanding: [W4A°, W4B°] (8, loaded in S-1 burst2).
//   ST8(S+1) -> 16.  ZRD16 (blk0,1).
//   F1 vmcnt(8) lgkm(0): retires W4A°+W4B° (L2-done, ~1 SS old); ST8 in flight.
//   burst1: 32 MFMA (wA,zA); W4A; 32 MFMA (wB,zB); W4B -> [ST8, W4A, W4B].
//   ZRD16 (blk2,3).
//   F2 vmcnt(0) lgkm(0): drains ST8 (age ~1400 cyc -> publication guaranteed
//     before the end-of-SS barrier) + burst1's W4s (age ~650 cyc, L2-done).
//   burst2: 32 MFMA (wA,zA); W4A'; 32 MFMA (wB,zB); W4B' -> [W4A',W4B'] steady.
//   s_barrier.  WAR (ring-2): ST8(S+1) -> buf (S+1)&1, read last in S-1, those
//   reads drained at S-1's F2 lgkm(0) before its end barrier.
//   Tail SS11: no ST8; F1 vmcnt(0) (only W4°s outstanding); burst1 loads
//   k46/k47; F2 vmcnt(0); burst2 loads nothing.  W chain: 2+44+2 = 48 ✓.
__global__ __launch_bounds__(256, 2) void qa_gemm(
    const unsigned short* __restrict__ xq,
    const unsigned short* __restrict__ xa,
    const unsigned short* __restrict__ wfr,
    const float* __restrict__ bias,
    float* __restrict__ out)
{
    __shared__ __align__(16) unsigned short lds[2 * 16384];   // 64 KB Z-ring

    const int bid = blockIdx.x;
    const int wg  = (bid & 7) * 160 + (bid >> 3);   // XCD swizzle, 1280 % 8 == 0

    const int ftBase = (wg & 1) * 256;
    const int lt     = wg >> 1;                     // 0..639, tile of 128 l-rows

    const unsigned short* xp;
    float* ob;
    int Mb, lsh, Lp;
    if (lt < 128) { Mb = lt * 128;         xp = xq; lsh = 6; Lp = LQ_ + 4; ob = out; }
    else          { Mb = (lt - 128) * 128; xp = xa; lsh = 8; Lp = LA_ + 4; ob = out + OUTQ_ELEMS; }
    const int Lv = 1 << lsh;

    const int tid  = threadIdx.x;
    const int lane = tid & 63;
    const int wid  = tid >> 6;      // wave = 64f slice; all share the 128l tile
    const int lq   = lane >> 4;
    const int lr   = lane & 15;
    const int s_c  = (lane & 3) ^ ((lane >> 3) & 3);
    const int sub  = lane >> 2;
    const int dzA  = wid * 1024;    // shorts: stage rows wid*32..+15
    const int dzB  = dzA + 512;     //          and +16..+31

    const int mr0 = Mb + wid * 32 + sub;
    const int mr1 = mr0 + 16;
    const unsigned short* gZ0 = xp + (size_t)((mr0 >> lsh) * Lp + (mr0 & (Lv - 1))) * EP + s_c * 8;
    const unsigned short* gZ1 = xp + (size_t)((mr1 >> lsh) * Lp + (mr1 & (Lv - 1))) * EP + s_c * 8;

    // ---- W fragment chains (verified layout); two sets, stride 2 kc per load
    const unsigned short* wpA0 = wfr + (size_t)((ftBase >> 4) + wid * 4 + 0) * NKT * 512 + lane * 8;
    const unsigned short* wpA1 = wfr + (size_t)((ftBase >> 4) + wid * 4 + 1) * NKT * 512 + lane * 8;
    const unsigned short* wpA2 = wfr + (size_t)((ftBase >> 4) + wid * 4 + 2) * NKT * 512 + lane * 8;
    const unsigned short* wpA3 = wfr + (size_t)((ftBase >> 4) + wid * 4 + 3) * NKT * 512 + lane * 8;
    const unsigned short* wpB0 = wpA0 + 512;
    const unsigned short* wpB1 = wpA1 + 512;
    const unsigned short* wpB2 = wpA2 + 512;
    const unsigned short* wpB3 = wpA3 + 512;

    // ---- Z fragment LDS offsets (bytes within a ksub blk; r8-verified family)
    const int cs = (lq ^ ((lr >> 1) & 3)) * 16;
    int zoff[8];
#pragma unroll
    for (int n = 0; n < 8; ++n) zoff[n] = (n * 16 + lr) * 64 + cs;

#define GLLDS(p, d) __builtin_amdgcn_global_load_lds(                               \
        (const __attribute__((address_space(1))) void*)(p),                         \
        (__attribute__((address_space(3))) void*)(d), 16, 0, 0)
#define ST8(T) do { const int rb = ((T) & 1) * 16384; const size_t ko = (size_t)(T) * 128; \
    _Pragma("unroll") for (int kb = 0; kb < 4; ++kb) {                              \
        GLLDS(gZ0 + ko + kb * 32, lds + rb + kb * 4096 + dzA);                      \
        GLLDS(gZ1 + ko + kb * 32, lds + rb + kb * 4096 + dzB); } } while (0)
#define WLOAD(dst, p) do {                                                           \
    asm volatile("global_load_dwordx4 %0, %1, off" : "=v"(dst) : "v"(p) : "memory"); \
    (p) += 1024; } while (0)
#define W4A do { WLOAD(wA[0], wpA0); WLOAD(wA[1], wpA1);                             \
                 WLOAD(wA[2], wpA2); WLOAD(wA[3], wpA3); } while (0)
#define W4B do { WLOAD(wB[0], wpB0); WLOAD(wB[1], wpB1);                             \
                 WLOAD(wB[2], wpB2); WLOAD(wB[3], wpB3); } while (0)
#define ZRD8(DST, BLK) do { _Pragma("unroll") for (int n = 0; n < 8; ++n)            \
    DST[n] = *(const short8*)(bbase + (BLK) * 8192 + zoff[n]); } while (0)
#define SB __builtin_amdgcn_sched_barrier(0)
#define FENCE(VM, LG) do {                                                           \
    asm volatile("s_waitcnt vmcnt(" #VM ") lgkmcnt(" #LG ")" ::: "memory"); SB; } while (0)
#define MFMA32K(WU, ZU) do { __builtin_amdgcn_s_setprio(1);                          \
    _Pragma("unroll") for (int mf = 0; mf < 4; ++mf)                                 \
    _Pragma("unroll") for (int nt = 0; nt < 8; ++nt)                                 \
        acc[mf][nt] = __builtin_amdgcn_mfma_f32_16x16x32_bf16(                       \
            WU[mf], ZU[nt], acc[mf][nt], 0, 0, 0);                                   \
    __builtin_amdgcn_s_setprio(0); SB; } while (0)

    f32x4 acc[4][8] = {};
    short8 zA[8], zB[8], wA[4], wB[4];

    // Prologue: wA(k0), wB(k1), stage ss0; drain; publish.
    W4A; W4B;
    ST8(0);
    asm volatile("s_waitcnt vmcnt(0)\n\ts_barrier" ::: "memory");

    for (int S = 0; S < 11; ++S) {
        ST8(S + 1);
        const char* bbase = (const char*)lds + (S & 1) * 32768;
        ZRD8(zA, 0); ZRD8(zB, 1);
        FENCE(8, 0);                        // retire W4A°,W4B°; ST8 in flight
        MFMA32K(wA, zA); W4A;
        MFMA32K(wB, zB); W4B;
        ZRD8(zA, 2); ZRD8(zB, 3);
        FENCE(0, 0);                        // drain ST8 (publish) + burst1 W4s
        MFMA32K(wA, zA); W4A;
        MFMA32K(wB, zB); W4B;
        asm volatile("s_barrier" ::: "memory");
    }
    {   // SS 11: no stage; burst1 loads k46/k47; burst2 loads nothing
        const char* bbase = (const char*)lds + 32768;
        ZRD8(zA, 0); ZRD8(zB, 1);
        FENCE(0, 0);
        MFMA32K(wA, zA); W4A;
        MFMA32K(wB, zB); W4B;
        ZRD8(zA, 2); ZRD8(zB, 3);
        FENCE(0, 0);
        MFMA32K(wA, zA);
        MFMA32K(wB, zB);
    }

#undef MFMA32K
#undef FENCE
#undef SB
#undef ZRD8
#undef W4A
#undef W4B
#undef WLOAD
#undef ST8
#undef GLLDS

    // ---- epilogue: D row = f = lq*4+reg, col = l = lr (verified r1-r15)
#pragma unroll
    for (int nt = 0; nt < 8; ++nt) {
        const int m = Mb + nt * 16 + lr;
        const int b = m >> lsh;
        const int l = m & (Lv - 1);
        float* orow = ob + ((size_t)b * F_ << lsh) + l;
#pragma unroll
        for (int mf = 0; mf < 4; ++mf) {
            const int f0 = ftBase + wid * 64 + mf * 16 + lq * 4;
            const f32x4 v = acc[mf][nt];
#pragma unroll
            for (int r = 0; r < 4; ++r)
                orow[(size_t)(f0 + r) << lsh] = v[r] + __ldg(&bias[f0 + r]);
        }
    }
}

extern "C" void kernel_launch(void* const* d_in, const int* in_sizes, int n_in,
                              void* d_out, int out_size, void* d_ws, size_t ws_size,
                              hipStream_t stream)
{
    const float* q    = (const float*)d_in[0];
    const float* a    = (const float*)d_in[1];
    const float* W    = (const float*)d_in[2];
    const float* bias = (const float*)d_in[3];
    float* out = (float*)d_out;

    unsigned short* xq  = (unsigned short*)d_ws;
    unsigned short* xa  = xq + XQ_ELEMS;
    unsigned short* wfr = xa + XA_ELEMS;
    // ws needed: (XQ+XA+WF)*2 = 52.6 MB.  xa K-pad tail reads overrun <=32 B
    // into wfr: in-bounds; the matching W fragments are zero -> don't-care.

    prep_all<<<XPBLK + WPBLK, 256, 0, stream>>>(q, a, W, xq, xa, wfr);
    qa_gemm<<<1280, 256, 0, stream>>>(xq, xa, wfr, bias, out);
}